// Round 2
// baseline (554.835 us; speedup 1.0000x reference)
//
#include <hip/hip_runtime.h>
#include <hip/hip_bf16.h>

#define B_ 16384
#define E_ 1024
#define H_ 8
#define D_ 128

typedef _Float16 f16;
typedef _Float16 f16x8 __attribute__((ext_vector_type(8)));
typedef float f32x4 __attribute__((ext_vector_type(4)));

// async global->LDS, 16B per lane; LDS dest = wave-uniform base + lane*16
__device__ __forceinline__ void load_lds16(const f16* g, f16* l) {
    __builtin_amdgcn_global_load_lds(
        (const __attribute__((address_space(1))) void*)g,
        (__attribute__((address_space(3))) void*)l, 16, 0, 0);
}

#define MFMA16(a, b, c) __builtin_amdgcn_mfma_f32_16x16x32_f16(a, b, c, 0, 0, 0)

// ---------------- X conversion: Xi16 = f16(image), Xd16 = f16(image - signal) ----------------
__global__ __launch_bounds__(256) void cvtX_kernel(
    const float4* __restrict__ im, const float4* __restrict__ sg,
    uint4* __restrict__ xi, uint4* __restrict__ xd, int n8)
{
    int i = blockIdx.x * 256 + threadIdx.x;
    if (i >= n8) return;
    float4 a0 = im[2 * i], a1 = im[2 * i + 1];
    float4 b0 = sg[2 * i], b1 = sg[2 * i + 1];
    union { uint4 u; f16 h[8]; } vi, vd;
    vi.h[0] = (f16)a0.x; vi.h[1] = (f16)a0.y; vi.h[2] = (f16)a0.z; vi.h[3] = (f16)a0.w;
    vi.h[4] = (f16)a1.x; vi.h[5] = (f16)a1.y; vi.h[6] = (f16)a1.z; vi.h[7] = (f16)a1.w;
    vd.h[0] = (f16)(a0.x - b0.x); vd.h[1] = (f16)(a0.y - b0.y);
    vd.h[2] = (f16)(a0.z - b0.z); vd.h[3] = (f16)(a0.w - b0.w);
    vd.h[4] = (f16)(a1.x - b1.x); vd.h[5] = (f16)(a1.y - b1.y);
    vd.h[6] = (f16)(a1.z - b1.z); vd.h[7] = (f16)(a1.w - b1.w);
    xi[i] = vi.u;
    xd[i] = vd.u;
}

// ---------------- W conversion: 4 weight matrices, blockIdx.y selects ----------------
__global__ __launch_bounds__(256) void cvtW_kernel(
    const float4* __restrict__ w0, const float4* __restrict__ w1,
    const float4* __restrict__ w2, const float4* __restrict__ w3,
    ushort4* __restrict__ d0, ushort4* __restrict__ d1,
    ushort4* __restrict__ d2, ushort4* __restrict__ d3, int n4)
{
    int i = blockIdx.x * 256 + threadIdx.x;
    if (i >= n4) return;
    const float4* s; ushort4* d;
    switch (blockIdx.y) {
        case 0: s = w0; d = d0; break;
        case 1: s = w1; d = d1; break;
        case 2: s = w2; d = d2; break;
        default: s = w3; d = d3; break;
    }
    float4 v = s[i];
    union { ushort4 u; f16 h[4]; } o;
    o.h[0] = (f16)v.x; o.h[1] = (f16)v.y; o.h[2] = (f16)v.z; o.h[3] = (f16)v.w;
    d[i] = o.u;
}

// ---------------- fused QKV + 2-key attention -> ctx ----------------
// delta = (Q+bq)·Kd, Kd = Xd@Wk^T ; ctx = Vi - a1*Vd + bv, a1 = 1/(1+exp(delta*scale))
// grid (B/128, H), 512 threads = 8 waves (2 row-groups x 4 col-groups), wave tile 64x32.
// LDS: fragment-contiguous (8 chunks of 1KB per 128x32 tile), filled via global_load_lds.
__global__ __launch_bounds__(512, 2) void qkv_kernel(
    const f16* __restrict__ Xi, const f16* __restrict__ Xd,
    const f16* __restrict__ Wq, const f16* __restrict__ Wk, const f16* __restrict__ Wv,
    const float* __restrict__ bq, const float* __restrict__ bv,
    f16* __restrict__ ctx)
{
    __shared__ f16 sXi[128 * 32];
    __shared__ f16 sXd[128 * 32];
    __shared__ f16 sWq[128 * 32];
    __shared__ f16 sWk[128 * 32];
    __shared__ f16 sWv[128 * 32];
    __shared__ float sdot[128][4];
    __shared__ float sa1[128];

    const int tid  = threadIdx.x;
    const int lane = tid & 63;
    const int w    = tid >> 6;      // 0..7
    const int wr   = w >> 2;        // 0..1 : 64-row group
    const int wc   = w & 3;         // 0..3 : 32-col group
    const int l16  = lane & 15, lq = lane >> 4;

    const int row0 = blockIdx.x * 128;
    const int col0 = blockIdx.y * D_;

    // staging: wave w fills chunk w of each tile; lane l -> (m=l&15, k=(l>>4)*8)
    const int srow = w * 16 + l16;
    const int skof = lq * 8;
    const f16* gXi = Xi + (size_t)(row0 + srow) * E_ + skof;
    const f16* gXd = Xd + (size_t)(row0 + srow) * E_ + skof;
    const f16* gWq = Wq + (size_t)(col0 + srow) * E_ + skof;
    const f16* gWk = Wk + (size_t)(col0 + srow) * E_ + skof;
    const f16* gWv = Wv + (size_t)(col0 + srow) * E_ + skof;
    f16* lXi = &sXi[w * 512];
    f16* lXd = &sXd[w * 512];
    f16* lWq = &sWq[w * 512];
    f16* lWk = &sWk[w * 512];
    f16* lWv = &sWv[w * 512];

    f32x4 zero = {0.f, 0.f, 0.f, 0.f};
    f32x4 aQ[4][2], aK[4][2], aVi[4][2], aVd[4][2];
    #pragma unroll
    for (int i = 0; i < 4; i++)
        #pragma unroll
        for (int j = 0; j < 2; j++) { aQ[i][j] = zero; aK[i][j] = zero; aVi[i][j] = zero; aVd[i][j] = zero; }

    for (int kk = 0; kk < E_; kk += 32) {
        load_lds16(gXi + kk, lXi);
        load_lds16(gXd + kk, lXd);
        load_lds16(gWq + kk, lWq);
        load_lds16(gWk + kk, lWk);
        load_lds16(gWv + kk, lWv);
        __syncthreads();   // drains vmcnt: LDS-writes visible

        f16x8 fI[4], fD[4], fQ[2], fK[2], fV[2];
        #pragma unroll
        for (int fr = 0; fr < 4; fr++) {
            fI[fr] = *(const f16x8*)&sXi[(wr * 4 + fr) * 512 + lane * 8];
            fD[fr] = *(const f16x8*)&sXd[(wr * 4 + fr) * 512 + lane * 8];
        }
        #pragma unroll
        for (int fc = 0; fc < 2; fc++) {
            fQ[fc] = *(const f16x8*)&sWq[(wc * 2 + fc) * 512 + lane * 8];
            fK[fc] = *(const f16x8*)&sWk[(wc * 2 + fc) * 512 + lane * 8];
            fV[fc] = *(const f16x8*)&sWv[(wc * 2 + fc) * 512 + lane * 8];
        }
        #pragma unroll
        for (int fr = 0; fr < 4; fr++)
            #pragma unroll
            for (int fc = 0; fc < 2; fc++) {
                aQ[fr][fc]  = MFMA16(fI[fr], fQ[fc], aQ[fr][fc]);
                aK[fr][fc]  = MFMA16(fD[fr], fK[fc], aK[fr][fc]);
                aVi[fr][fc] = MFMA16(fI[fr], fV[fc], aVi[fr][fc]);
                aVd[fr][fc] = MFMA16(fD[fr], fV[fc], aVd[fr][fc]);
            }
        __syncthreads();   // all reads done before next iter's loads overwrite
    }

    // ---- delta = (Q+bq)·Kd per row, reduced over this wave's 32 cols, then cross-wave ----
    float bqv[2];
    #pragma unroll
    for (int fc = 0; fc < 2; fc++) bqv[fc] = bq[col0 + wc * 32 + fc * 16 + l16];
    #pragma unroll
    for (int fr = 0; fr < 4; fr++)
        #pragma unroll
        for (int e = 0; e < 4; e++) {
            float d = 0.f;
            #pragma unroll
            for (int fc = 0; fc < 2; fc++)
                d += (aQ[fr][fc][e] + bqv[fc]) * aK[fr][fc][e];
            d += __shfl_xor(d, 1, 64);
            d += __shfl_xor(d, 2, 64);
            d += __shfl_xor(d, 4, 64);
            d += __shfl_xor(d, 8, 64);
            if (l16 == 0) sdot[wr * 64 + fr * 16 + lq * 4 + e][wc] = d;
        }
    __syncthreads();
    if (tid < 128) {
        const float scale = 0.088388347648318447f;  // 1/sqrt(128)
        float delta = (sdot[tid][0] + sdot[tid][1] + sdot[tid][2] + sdot[tid][3]) * scale;
        sa1[tid] = 1.0f / (1.0f + __expf(delta));   // a1 = softmax weight of signal key
    }
    __syncthreads();

    // ---- ctx = Vi - a1*Vd + bv ----
    #pragma unroll
    for (int fc = 0; fc < 2; fc++) {
        int col = col0 + wc * 32 + fc * 16 + l16;
        float bvv = bv[col];
        #pragma unroll
        for (int fr = 0; fr < 4; fr++)
            #pragma unroll
            for (int e = 0; e < 4; e++) {
                int row = wr * 64 + fr * 16 + lq * 4 + e;
                float a1r = sa1[row];
                ctx[(size_t)(row0 + row) * E_ + col] =
                    (f16)(aVi[fr][fc][e] - a1r * aVd[fr][fc][e] + bvv);
            }
    }
}

// ---------------- out projection: ctx @ Wo^T + bo + residual -> f32 (m97 structure) ----------------
__global__ __launch_bounds__(256) void out_proj_kernel(
    const f16* __restrict__ A, const f16* __restrict__ Wo,
    const float* __restrict__ bo, const float* __restrict__ resid,
    float* __restrict__ out)
{
    __shared__ f16 sA[128 * 32];
    __shared__ f16 sB[128 * 32];
    const int tid  = threadIdx.x;
    const int lane = tid & 63;
    const int w    = tid >> 6;      // 0..3
    const int wr   = w >> 1, wc = w & 1;
    const int l16  = lane & 15, lq = lane >> 4;
    const int row0 = blockIdx.x * 128;
    const int col0 = blockIdx.y * 128;

    // staging: wave w fills chunks 2w, 2w+1 of each tile
    const int sr0 = (2 * w) * 16 + l16;
    const int sr1 = (2 * w + 1) * 16 + l16;
    const int skof = lq * 8;
    const f16* gA0 = A  + (size_t)(row0 + sr0) * E_ + skof;
    const f16* gA1 = A  + (size_t)(row0 + sr1) * E_ + skof;
    const f16* gB0 = Wo + (size_t)(col0 + sr0) * E_ + skof;
    const f16* gB1 = Wo + (size_t)(col0 + sr1) * E_ + skof;
    f16* lA0 = &sA[(2 * w) * 512];
    f16* lA1 = &sA[(2 * w + 1) * 512];
    f16* lB0 = &sB[(2 * w) * 512];
    f16* lB1 = &sB[(2 * w + 1) * 512];

    f32x4 zero = {0.f, 0.f, 0.f, 0.f};
    f32x4 acc[4][4];
    #pragma unroll
    for (int i = 0; i < 4; i++)
        #pragma unroll
        for (int j = 0; j < 4; j++) acc[i][j] = zero;

    for (int kk = 0; kk < E_; kk += 32) {
        load_lds16(gA0 + kk, lA0);
        load_lds16(gA1 + kk, lA1);
        load_lds16(gB0 + kk, lB0);
        load_lds16(gB1 + kk, lB1);
        __syncthreads();

        f16x8 aF[4], bF[4];
        #pragma unroll
        for (int f = 0; f < 4; f++) {
            aF[f] = *(const f16x8*)&sA[(wr * 4 + f) * 512 + lane * 8];
            bF[f] = *(const f16x8*)&sB[(wc * 4 + f) * 512 + lane * 8];
        }
        #pragma unroll
        for (int fr = 0; fr < 4; fr++)
            #pragma unroll
            for (int fc = 0; fc < 4; fc++)
                acc[fr][fc] = MFMA16(aF[fr], bF[fc], acc[fr][fc]);
        __syncthreads();
    }

    #pragma unroll
    for (int fc = 0; fc < 4; fc++) {
        int col = col0 + wc * 64 + fc * 16 + l16;
        float bov = bo[col];
        #pragma unroll
        for (int fr = 0; fr < 4; fr++)
            #pragma unroll
            for (int e = 0; e < 4; e++) {
                int row = row0 + wr * 64 + fr * 16 + lq * 4 + e;
                out[(size_t)row * E_ + col] = acc[fr][fc][e] + bov + resid[(size_t)row * E_ + col];
            }
    }
}

// ---------------- in-place LayerNorm over E=1024 ----------------
__global__ __launch_bounds__(256) void ln_kernel(
    float* __restrict__ x, const float* __restrict__ gamma,
    const float* __restrict__ beta, float* __restrict__ out)
{
    const int row = blockIdx.x;
    const int tid = threadIdx.x;
    const float4* xr = (const float4*)(x + (size_t)row * E_);
    float4 v = xr[tid];
    float s  = v.x + v.y + v.z + v.w;
    float s2 = v.x * v.x + v.y * v.y + v.z * v.z + v.w * v.w;
    #pragma unroll
    for (int m = 1; m < 64; m <<= 1) {
        s  += __shfl_xor(s, m, 64);
        s2 += __shfl_xor(s2, m, 64);
    }
    __shared__ float red[8];
    int wv = tid >> 6, ln = tid & 63;
    if (ln == 0) { red[wv] = s; red[4 + wv] = s2; }
    __syncthreads();
    s  = red[0] + red[1] + red[2] + red[3];
    s2 = red[4] + red[5] + red[6] + red[7];
    float mu  = s * (1.0f / E_);
    float var = s2 * (1.0f / E_) - mu * mu;
    float r   = rsqrtf(var + 1e-5f);
    float4 g  = ((const float4*)gamma)[tid];
    float4 bb = ((const float4*)beta)[tid];
    float4 o;
    o.x = (v.x - mu) * r * g.x + bb.x;
    o.y = (v.y - mu) * r * g.y + bb.y;
    o.z = (v.z - mu) * r * g.z + bb.z;
    o.w = (v.w - mu) * r * g.w + bb.w;
    ((float4*)(out + (size_t)row * E_))[tid] = o;
}

extern "C" void kernel_launch(void* const* d_in, const int* in_sizes, int n_in,
                              void* d_out, int out_size, void* d_ws, size_t ws_size,
                              hipStream_t stream)
{
    (void)in_sizes; (void)n_in; (void)out_size; (void)ws_size;
    const float* image  = (const float*)d_in[0];
    const float* signal = (const float*)d_in[1];
    const float* Wq = (const float*)d_in[2];
    const float* Wk = (const float*)d_in[3];
    const float* Wv = (const float*)d_in[4];
    const float* bq = (const float*)d_in[5];
    const float* bv = (const float*)d_in[7];
    const float* Wo = (const float*)d_in[8];
    const float* bo = (const float*)d_in[9];
    const float* gamma = (const float*)d_in[10];
    const float* beta  = (const float*)d_in[11];
    float* out = (float*)d_out;

    char* ws = (char*)d_ws;
    f16* Xi16 = (f16*)(ws);                            // 32 MB
    f16* Xd16 = (f16*)(ws + 32ull * 1024 * 1024);      // 32 MB
    f16* Wq16 = (f16*)(ws + 64ull * 1024 * 1024);      // 2 MB
    f16* Wk16 = (f16*)(ws + 66ull * 1024 * 1024);      // 2 MB
    f16* Wv16 = (f16*)(ws + 68ull * 1024 * 1024);      // 2 MB
    f16* Wo16 = (f16*)(ws + 70ull * 1024 * 1024);      // 2 MB
    f16* ctx  = (f16*)(ws + 72ull * 1024 * 1024);      // 32 MB

    const int n8  = B_ * E_ / 8;    // 2097152
    const int n4w = E_ * E_ / 4;    // 262144
    cvtX_kernel<<<n8 / 256, 256, 0, stream>>>((const float4*)image, (const float4*)signal,
                                              (uint4*)Xi16, (uint4*)Xd16, n8);
    dim3 gw(n4w / 256, 4);
    cvtW_kernel<<<gw, 256, 0, stream>>>((const float4*)Wq, (const float4*)Wk,
                                        (const float4*)Wv, (const float4*)Wo,
                                        (ushort4*)Wq16, (ushort4*)Wk16,
                                        (ushort4*)Wv16, (ushort4*)Wo16, n4w);

    dim3 gq(B_ / 128, H_);
    qkv_kernel<<<gq, 512, 0, stream>>>(Xi16, Xd16, Wq16, Wk16, Wv16, bq, bv, ctx);

    dim3 go(B_ / 128, E_ / 128);
    out_proj_kernel<<<go, 256, 0, stream>>>(ctx, Wo16, bo, image, out);

    ln_kernel<<<B_, 256, 0, stream>>>(out, gamma, beta, out);
}